// Round 2
// baseline (402.282 us; speedup 1.0000x reference)
//
#include <hip/hip_runtime.h>
#include <hip/hip_bf16.h>
#include <stdint.h>

// NRI fixed encoder. Output [B=32, E=159600, 2] where E = N*(N-1), N=400,
// edges in np.where(~eye) row-major order:
//   send = e / 399; k = e % 399; rec = k + (k >= send)
// t = (adj[send,rec] != 0); out pair = (1-t, t), identical for all batches.
//
// Harness dtype is ambiguous (fp32 reference, but test has a bf16 read path).
// Runtime-detect adj dtype: values are exactly {0.0, 1.0}. Viewed as u16:
//   fp32 buffer -> every EVEN half-word is 0x0000 (low half of 0.0f/1.0f)
//   bf16 buffer -> ~50% of entries are 0x3F80
// Probe 64 even u16s; any nonzero => bf16 mode. Assume output dtype matches.

#define N_NODES 400
#define N_EDGES (N_NODES * (N_NODES - 1))   // 159600
#define BATCH   32
#define E4      (N_EDGES / 4)               // 39900

__global__ void detect_dtype_kernel(const uint16_t* __restrict__ adj_u16,
                                    int* __restrict__ flag) {
    if (threadIdx.x == 0 && blockIdx.x == 0) {
        int f = 0;
        for (int i = 0; i < 64; ++i) f |= (adj_u16[2 * i] != 0) ? 1 : 0;
        *flag = f;   // 1 => bf16 buffers, 0 => fp32 buffers
    }
}

__global__ __launch_bounds__(256)
void nri_edge_onehot_kernel(const void* __restrict__ adj,
                            const int* __restrict__ flag_p,
                            void* __restrict__ out) {
    const int idx = blockIdx.x * blockDim.x + threadIdx.x;   // [0, BATCH*E4)
    if (idx >= BATCH * E4) return;

    const int is_bf16 = *flag_p;   // wave-uniform scalar load, no divergence

    const int e4 = idx % E4;       // same edge group for every batch
    const int e0 = e4 * 4;

    bool t[4];
#pragma unroll
    for (int j = 0; j < 4; ++j) {
        const int e    = e0 + j;
        const int send = e / (N_NODES - 1);
        const int k    = e - send * (N_NODES - 1);
        const int rec  = k + (k >= send ? 1 : 0);
        const int a    = send * N_NODES + rec;
        if (is_bf16) {
            t[j] = (((const uint16_t*)adj)[a] & 0x7FFF) != 0;
        } else {
            t[j] = ((const float*)adj)[a] != 0.0f;
        }
    }

    if (is_bf16) {
        // pair (1-t, t) as bf16 packed in u32: t=0 -> 0x00003F80, t=1 -> 0x3F800000
        uint32_t w[4];
#pragma unroll
        for (int j = 0; j < 4; ++j)
            w[j] = t[j] ? 0x3F800000u : 0x00003F80u;
        ((uint4*)out)[idx] = make_uint4(w[0], w[1], w[2], w[3]);
    } else {
        // fp32: 4 edges = 8 floats = 2 × float4, coalesced
        float4 lo = make_float4(t[0] ? 0.f : 1.f, t[0] ? 1.f : 0.f,
                                t[1] ? 0.f : 1.f, t[1] ? 1.f : 0.f);
        float4 hi = make_float4(t[2] ? 0.f : 1.f, t[2] ? 1.f : 0.f,
                                t[3] ? 0.f : 1.f, t[3] ? 1.f : 0.f);
        ((float4*)out)[2 * idx + 0] = lo;
        ((float4*)out)[2 * idx + 1] = hi;
    }
}

extern "C" void kernel_launch(void* const* d_in, const int* in_sizes, int n_in,
                              void* d_out, int out_size, void* d_ws, size_t ws_size,
                              hipStream_t stream) {
    // setup_inputs order: inputs, weather, rel_rec, rel_send, adj_matrix
    const void* adj = d_in[4];         // [400,400], dtype detected at runtime
    int* flag = (int*)d_ws;            // re-poisoned each call; rewritten here

    detect_dtype_kernel<<<1, 64, 0, stream>>>((const uint16_t*)adj, flag);

    const int total = BATCH * E4;      // 1,276,800 threads
    const int block = 256;
    const int grid  = (total + block - 1) / block;
    nri_edge_onehot_kernel<<<grid, block, 0, stream>>>(adj, flag, d_out);
}

// Round 3
// 392.392 us; speedup vs baseline: 1.0252x; 1.0252x over previous
//
#include <hip/hip_runtime.h>
#include <hip/hip_bf16.h>
#include <stdint.h>

// NRI fixed encoder. Output [B=32, E=159600, 2] where E = N*(N-1), N=400,
// edges in np.where(~eye) row-major order:
//   send = e / 399; k = e % 399; rec = k + (k >= send)
// t = (adj[send,rec] != 0); out pair = (1-t, t), identical for all batches.
//
// Harness may present buffers as fp32 or bf16. Per-wave runtime detection:
// adj values are exactly {0.0, 1.0}. Viewed as u16, an fp32 buffer has every
// EVEN half-word == 0 (low half of 0.0f/1.0f); a bf16 buffer has ~50% 0x3F80.
// Each lane probes adj_u16[2*lane]; __ballot != 0 => bf16. Wave-uniform,
// P(false negative) = 2^-64. This removes the separate detect kernel.
//
// dur_us is dominated by the harness reset stream (1 GB ws poison at 83% HBM
// peak, 510 MB one-hot input restore); kernel-side floor is the 20-41 MB
// output write (~6 us at 6.6 TB/s).

#define N_NODES 400
#define N_EDGES (N_NODES * (N_NODES - 1))   // 159600
#define BATCH   32
#define E2      (N_EDGES / 2)               // 79800  (fp32: 2 edges -> 1 float4)
#define E4      (N_EDGES / 4)               // 39900  (bf16: 4 edges -> 1 uint4)

__global__ __launch_bounds__(256)
void nri_edge_onehot_kernel(const void* __restrict__ adj,
                            void* __restrict__ out) {
    const int idx = blockIdx.x * blockDim.x + threadIdx.x;   // [0, BATCH*E2)

    // ---- per-wave dtype probe (wave-uniform, no divergence) ----
    const uint16_t* adj_u16 = (const uint16_t*)adj;
    const int lane = threadIdx.x & 63;
    const unsigned long long b = __ballot(adj_u16[2 * lane] != 0);
    const bool is_bf16 = (b != 0ull);

    if (!is_bf16) {
        // fp32 mode: thread idx -> float4 at out[idx], covering edges e0, e0+1
        if (idx >= BATCH * E2) return;
        const int ep = idx % E2;
        const int e0 = ep * 2;
        float v[4];
#pragma unroll
        for (int j = 0; j < 2; ++j) {
            const int e    = e0 + j;
            const int send = e / (N_NODES - 1);
            const int k    = e - send * (N_NODES - 1);
            const int rec  = k + (k >= send ? 1 : 0);
            const bool t   = ((const float*)adj)[send * N_NODES + rec] != 0.0f;
            v[2 * j]     = t ? 0.f : 1.f;
            v[2 * j + 1] = t ? 1.f : 0.f;
        }
        ((float4*)out)[idx] = make_float4(v[0], v[1], v[2], v[3]);
    } else {
        // bf16 mode: thread idx -> uint4 at out[idx], covering edges e0..e0+3
        // pair (1-t, t) as bf16 packed u32: t=0 -> 0x00003F80, t=1 -> 0x3F800000
        if (idx >= BATCH * E4) return;
        const int e4 = idx % E4;
        const int e0 = e4 * 4;
        uint32_t w[4];
#pragma unroll
        for (int j = 0; j < 4; ++j) {
            const int e    = e0 + j;
            const int send = e / (N_NODES - 1);
            const int k    = e - send * (N_NODES - 1);
            const int rec  = k + (k >= send ? 1 : 0);
            const bool t   = (adj_u16[send * N_NODES + rec] & 0x7FFF) != 0;
            w[j] = t ? 0x3F800000u : 0x00003F80u;
        }
        ((uint4*)out)[idx] = make_uint4(w[0], w[1], w[2], w[3]);
    }
}

extern "C" void kernel_launch(void* const* d_in, const int* in_sizes, int n_in,
                              void* d_out, int out_size, void* d_ws, size_t ws_size,
                              hipStream_t stream) {
    // setup_inputs order: inputs, weather, rel_rec, rel_send, adj_matrix
    const void* adj = d_in[4];          // [400,400], dtype detected in-kernel

    const int total = BATCH * E2;       // 2,553,600 threads (fp32 sizing; bf16
    const int block = 256;              // mode retires the upper half early)
    const int grid  = (total + block - 1) / block;
    nri_edge_onehot_kernel<<<grid, block, 0, stream>>>(adj, d_out);
}